// Round 2
// baseline (167.999 us; speedup 1.0000x reference)
//
#include <hip/hip_runtime.h>

#define NN 4096
#define FF 512
#define DD 64
#define HH 8
#define CC 40
#define HD (HH * DD)   // 512
#define CP 64          // padded class dim
#define MAXDEG 128
#define ALPHA 0.2f

// l2 fused GEMM tiling
#define L2BM 16
#define L2BK 32

typedef __attribute__((ext_vector_type(8))) short bf16x8;
typedef __attribute__((ext_vector_type(4))) float f32x4;

__device__ __forceinline__ float bf2f(unsigned short u) {
    union { unsigned int i; float f; } v;
    v.i = ((unsigned int)u) << 16;
    return v.f;
}

__device__ __forceinline__ unsigned short f2bf(float f) {
    union { float f; unsigned int u; } v;
    v.f = f;
    unsigned int r = v.u + 0x7fffu + ((v.u >> 16) & 1u);  // RNE
    return (unsigned short)(r >> 16);
}

__device__ __forceinline__ float wave_sum(float v) {
    #pragma unroll
    for (int off = 32; off; off >>= 1) v += __shfl_xor(v, off, 64);
    return v;
}

__device__ __forceinline__ float wave_max(float v) {
    #pragma unroll
    for (int off = 32; off; off >>= 1) v = fmaxf(v, __shfl_xor(v, off, 64));
    return v;
}

__device__ __forceinline__ float read_f(const void* src, int i, int isBf16) {
    if (isBf16) return bf2f(((const unsigned short*)src)[i]);
    return ((const float*)src)[i];
}

// Inline x-dtype sniff: every block reads the SAME x[0:1024] words (4KB,
// L2-hit) -> all blocks reach the same verdict deterministically.
__device__ __forceinline__ int sniff_x(const void* xraw, int tid, int* fS) {
    if (tid == 0) *fS = 1;
    __syncthreads();
    int bad = 0;
    const unsigned int* xw = (const unsigned int*)xraw;
    #pragma unroll
    for (int q = 0; q < 4; q++) {
        unsigned int w = xw[(tid & 255) * 4 + q];
        unsigned int e0 = (w >> 7) & 0xffu;
        unsigned int e1 = (w >> 23) & 0xffu;
        if (e0 >= 0x90u || e1 >= 0x90u) bad = 1;
    }
    if (bad) *fS = 0;
    __syncthreads();
    return *fS;
}

// ---------------- prep: build_nbr + all conversions in ONE launch -----------
// NOTE (R14 post-mortem): do NOT fuse the l2 split-K reduction into l2_gemm
// via global atomicAdd — cross-XCD f32 atomics resolve at the fabric
// coherence point (per-XCD L2s non-coherent) and cost +16.5 us vs an
// L2-resident partials round-trip. (R1: split-K removed entirely instead.)
__global__ __launch_bounds__(256) void prep(const unsigned char* __restrict__ adj,
                                            const void* __restrict__ x,
                                            const void* __restrict__ W1,
                                            const void* __restrict__ W2,
                                            const void* __restrict__ a1s,
                                            const void* __restrict__ a1d,
                                            const void* __restrict__ a2s,
                                            const void* __restrict__ a2d,
                                            int* __restrict__ nbr,
                                            int* __restrict__ deg,
                                            unsigned short* __restrict__ W1bth,
                                            unsigned short* __restrict__ W1btl,
                                            float* __restrict__ W2p,
                                            float* __restrict__ a1sf,
                                            float* __restrict__ a1df,
                                            float* __restrict__ a2sf,
                                            float* __restrict__ a2df) {
    __shared__ int cnt;
    __shared__ int fS;
    int t = threadIdx.x;
    int blk = blockIdx.x;

    if (blk < NN) {
        // ---- build_nbr path; adj elem-size sniff: byte t*(NN+1) (valid in
        // both layouts). Byte-bool: diagonal -> all 1. Int32: t%4!=0 hits a
        // zero byte-lane of a 0/1 word -> 0.
        if (t == 0) { cnt = 0; fS = 1; }
        __syncthreads();
        if (adj[(size_t)t * (NN + 1)] == 0) fS = 0;  // benign race
        __syncthreads();
        int isByte = fS;
        int i = blk;
        if (isByte) {
            uint4 v = ((const uint4*)(adj + (size_t)i * NN))[t];
            unsigned int u[4] = { v.x, v.y, v.z, v.w };
            int base = t * 16;
            #pragma unroll
            for (int q = 0; q < 4; q++) {
                #pragma unroll
                for (int b = 0; b < 4; b++) {
                    if ((u[q] >> (8 * b)) & 0xffu) {
                        int p = atomicAdd(&cnt, 1);
                        if (p < MAXDEG) nbr[(size_t)i * MAXDEG + p] = base + q * 4 + b;
                    }
                }
            }
        } else {
            const int4* row = (const int4*)((const int*)adj + (size_t)i * NN);
            #pragma unroll
            for (int q = 0; q < 4; q++) {
                int idx4 = q * 256 + t;
                int4 v = row[idx4];
                int base = idx4 * 4;
                if (v.x) { int p = atomicAdd(&cnt, 1); if (p < MAXDEG) nbr[(size_t)i * MAXDEG + p] = base; }
                if (v.y) { int p = atomicAdd(&cnt, 1); if (p < MAXDEG) nbr[(size_t)i * MAXDEG + p] = base + 1; }
                if (v.z) { int p = atomicAdd(&cnt, 1); if (p < MAXDEG) nbr[(size_t)i * MAXDEG + p] = base + 2; }
                if (v.w) { int p = atomicAdd(&cnt, 1); if (p < MAXDEG) nbr[(size_t)i * MAXDEG + p] = base + 3; }
            }
        }
        __syncthreads();
        if (t == 0) deg[i] = min(cnt, MAXDEG);
        return;
    }

    int bf = sniff_x(x, t, &fS);

    if (blk < NN + 64) {
        // ---- W1 transpose path: thread owns 16 consecutive OUTPUT elems
        // (32B coalesced store per array); reads are stride-DD, L2-resident.
        int b = blk - NN;                       // 0..63
        int ob = b * 4096 + t * 16;             // output elem base (262,144 tot)
        int row = ob >> 9;                      // hd*64 + d
        int f0 = ob & 511;
        int hd = row >> 6, d = row & 63;
        unsigned short hi[16], lo[16];
        #pragma unroll
        for (int q = 0; q < 16; q++) {
            float v = read_f(W1, (hd * FF + f0 + q) * DD + d, bf);
            unsigned short h16 = f2bf(v);
            hi[q] = h16;
            lo[q] = f2bf(v - bf2f(h16));
        }
        #pragma unroll
        for (int q = 0; q < 16; q++) {
            W1bth[(size_t)row * FF + f0 + q] = hi[q];
            W1btl[(size_t)row * FF + f0 + q] = lo[q];
        }
        return;
    }

    // ---- small tensors: W2p (zero-padded), a-vectors
    int i = (blk - NN - 64) * 256 + t;
    const int nW2p = HD * CP;          // 32,768
    const int nA1 = HD;                // 512
    if (i < nW2p) {
        int k = i / CP, c = i % CP;
        W2p[i] = (c < CC) ? read_f(W2, k * CC + c, bf) : 0.f;
        return;
    }
    i -= nW2p;
    if (i < nA1) { a1sf[i] = read_f(a1s, i, bf); return; }
    i -= nA1;
    if (i < nA1) { a1df[i] = read_f(a1d, i, bf); return; }
    i -= nA1;
    if (i < CC) { a2sf[i] = read_f(a2s, i, bf); return; }
    i -= CC;
    if (i < CC) { a2df[i] = read_f(a2d, i, bf); return; }
}

// ------ l1 GEMM via MFMA bf16x3, native x; si/sj via LDS (no atomics) -------
__global__ __launch_bounds__(256) void l1_gemm(const void* __restrict__ xraw,
                                               const unsigned short* __restrict__ W1bth,
                                               const unsigned short* __restrict__ W1btl,
                                               const float* __restrict__ a1sf,
                                               const float* __restrict__ a1df,
                                               unsigned short* __restrict__ hb,
                                               float* __restrict__ si,
                                               float* __restrict__ sj) {
    __shared__ __align__(16) unsigned short Ah[64][40];
    __shared__ __align__(16) unsigned short Al[64][40];
    __shared__ __align__(16) unsigned short Bh[64][40];
    __shared__ __align__(16) unsigned short Bl[64][40];
    __shared__ int fS;

    int bm = blockIdx.x, hd = blockIdx.y;
    int tid = threadIdx.x;
    int isBf16 = sniff_x(xraw, tid, &fS);

    int wave = tid >> 6, lane = tid & 63;
    int wm = wave >> 1, wn = wave & 1;
    int lr = lane & 15, lg = lane >> 4;
    int srow = tid >> 2;
    int sseg = (tid & 3) * 8;

    const unsigned short* wAp = W1bth + (size_t)(hd * 64 + srow) * FF + sseg;
    const unsigned short* wBp = W1btl + (size_t)(hd * 64 + srow) * FF + sseg;

    f32x4 acc[2][2];
    #pragma unroll
    for (int r = 0; r < 2; r++)
        #pragma unroll
        for (int c = 0; c < 2; c++) acc[r][c] = (f32x4){0.f, 0.f, 0.f, 0.f};

    if (isBf16) {
        const unsigned short* xp = (const unsigned short*)xraw
                                 + (size_t)(bm * 64 + srow) * FF + sseg;
        uint4 ra = *(const uint4*)xp;
        uint4 rb = *(const uint4*)wAp;
        for (int kk = 0; kk < FF; kk += 32) {
            __syncthreads();
            *(uint4*)&Ah[srow][sseg] = ra;
            *(uint4*)&Bh[srow][sseg] = rb;
            __syncthreads();
            int kn = (kk + 32 < FF) ? kk + 32 : kk;
            ra = *(const uint4*)(xp + kn);
            rb = *(const uint4*)(wAp + kn);
            bf16x8 a0 = *(const bf16x8*)&Ah[wm * 32 + lr][lg * 8];
            bf16x8 a1 = *(const bf16x8*)&Ah[wm * 32 + 16 + lr][lg * 8];
            bf16x8 b0 = *(const bf16x8*)&Bh[wn * 32 + lr][lg * 8];
            bf16x8 b1 = *(const bf16x8*)&Bh[wn * 32 + 16 + lr][lg * 8];
            acc[0][0] = __builtin_amdgcn_mfma_f32_16x16x32_bf16(a0, b0, acc[0][0], 0, 0, 0);
            acc[0][1] = __builtin_amdgcn_mfma_f32_16x16x32_bf16(a0, b1, acc[0][1], 0, 0, 0);
            acc[1][0] = __builtin_amdgcn_mfma_f32_16x16x32_bf16(a1, b0, acc[1][0], 0, 0, 0);
            acc[1][1] = __builtin_amdgcn_mfma_f32_16x16x32_bf16(a1, b1, acc[1][1], 0, 0, 0);
        }
    } else {
        const float* xp = (const float*)xraw + (size_t)(bm * 64 + srow) * FF + sseg;
        float4 ra0 = *(const float4*)xp;
        float4 ra1 = *(const float4*)(xp + 4);
        uint4 rbh = *(const uint4*)wAp;
        uint4 rbl = *(const uint4*)wBp;
        for (int kk = 0; kk < FF; kk += 32) {
            __syncthreads();
            union { unsigned short s[8]; uint4 v; } uh, ul;
            float fv[8] = { ra0.x, ra0.y, ra0.z, ra0.w, ra1.x, ra1.y, ra1.z, ra1.w };
            #pragma unroll
            for (int q = 0; q < 8; q++) {
                unsigned short h16 = f2bf(fv[q]);
                uh.s[q] = h16;
                ul.s[q] = f2bf(fv[q] - bf2f(h16));
            }
            *(uint4*)&Ah[srow][sseg] = uh.v;
            *(uint4*)&Al[srow][sseg] = ul.v;
            *(uint4*)&Bh[srow][sseg] = rbh;
            *(uint4*)&Bl[srow][sseg] = rbl;
            __syncthreads();
            int kn = (kk + 32 < FF) ? kk + 32 : kk;
            ra0 = *(const float4*)(xp + kn);
            ra1 = *(const float4*)(xp + kn + 4);
            rbh = *(const uint4*)(wAp + kn);
            rbl = *(const uint4*)(wBp + kn);

            bf16x8 a_h0 = *(const bf16x8*)&Ah[wm * 32 + lr][lg * 8];
            bf16x8 a_h1 = *(const bf16x8*)&Ah[wm * 32 + 16 + lr][lg * 8];
            bf16x8 a_l0 = *(const bf16x8*)&Al[wm * 32 + lr][lg * 8];
            bf16x8 a_l1 = *(const bf16x8*)&Al[wm * 32 + 16 + lr][lg * 8];
            bf16x8 b_h0 = *(const bf16x8*)&Bh[wn * 32 + lr][lg * 8];
            bf16x8 b_h1 = *(const bf16x8*)&Bh[wn * 32 + 16 + lr][lg * 8];
            bf16x8 b_l0 = *(const bf16x8*)&Bl[wn * 32 + lr][lg * 8];
            bf16x8 b_l1 = *(const bf16x8*)&Bl[wn * 32 + 16 + lr][lg * 8];

            acc[0][0] = __builtin_amdgcn_mfma_f32_16x16x32_bf16(a_h0, b_h0, acc[0][0], 0, 0, 0);
            acc[0][1] = __builtin_amdgcn_mfma_f32_16x16x32_bf16(a_h0, b_h1, acc[0][1], 0, 0, 0);
            acc[1][0] = __builtin_amdgcn_mfma_f32_16x16x32_bf16(a_h1, b_h0, acc[1][0], 0, 0, 0);
            acc[1][1] = __builtin_amdgcn_mfma_f32_16x16x32_bf16(a_h1, b_h1, acc[1][1], 0, 0, 0);
            acc[0][0] = __builtin_amdgcn_mfma_f32_16x16x32_bf16(a_h0, b_l0, acc[0][0], 0, 0, 0);
            acc[0][1] = __builtin_amdgcn_mfma_f32_16x16x32_bf16(a_h0, b_l1, acc[0][1], 0, 0, 0);
            acc[1][0] = __builtin_amdgcn_mfma_f32_16x16x32_bf16(a_h1, b_l0, acc[1][0], 0, 0, 0);
            acc[1][1] = __builtin_amdgcn_mfma_f32_16x16x32_bf16(a_h1, b_l1, acc[1][1], 0, 0, 0);
            acc[0][0] = __builtin_amdgcn_mfma_f32_16x16x32_bf16(a_l0, b_h0, acc[0][0], 0, 0, 0);
            acc[0][1] = __builtin_amdgcn_mfma_f32_16x16x32_bf16(a_l0, b_h1, acc[0][1], 0, 0, 0);
            acc[1][0] = __builtin_amdgcn_mfma_f32_16x16x32_bf16(a_l1, b_h0, acc[1][0], 0, 0, 0);
            acc[1][1] = __builtin_amdgcn_mfma_f32_16x16x32_bf16(a_l1, b_h1, acc[1][1], 0, 0, 0);
        }
    }

    // epilogue: h writes + si/sj partials reduced across the two wn-waves
    // via LDS (reuse Ah as float scratch; no global atomics).
    float adv[2], asv[2];
    #pragma unroll
    for (int fc = 0; fc < 2; fc++) {
        adv[fc] = a1df[hd * DD + wn * 32 + fc * 16 + lr];
        asv[fc] = a1sf[hd * DD + wn * 32 + fc * 16 + lr];
    }
    float pdv[2][4], psv[2][4];
    #pragma unroll
    for (int fr = 0; fr < 2; fr++) {
        #pragma unroll
        for (int q = 0; q < 4; q++) {
            int row = bm * 64 + wm * 32 + fr * 16 + lg * 4 + q;
            int colb = hd * 64 + wn * 32;
            hb[(size_t)row * HD + colb + lr] = f2bf(acc[fr][0][q]);
            hb[(size_t)row * HD + colb + 16 + lr] = f2bf(acc[fr][1][q]);
            float pd = acc[fr][0][q] * adv[0] + acc[fr][1][q] * adv[1];
            float ps = acc[fr][0][q] * asv[0] + acc[fr][1][q] * asv[1];
            #pragma unroll
            for (int off = 1; off < 16; off <<= 1) {
                pd += __shfl_xor(pd, off, 64);
                ps += __shfl_xor(ps, off, 64);
            }
            pdv[fr][q] = pd;
            psv[fr][q] = ps;
        }
    }
    float* sred = (float*)&Ah[0][0];  // 64 rows x {si,sj} = 512B
    __syncthreads();
    if (wn == 0 && lr == 0) {
        #pragma unroll
        for (int fr = 0; fr < 2; fr++)
            #pragma unroll
            for (int q = 0; q < 4; q++) {
                int rl = wm * 32 + fr * 16 + lg * 4 + q;
                sred[rl * 2] = pdv[fr][q];
                sred[rl * 2 + 1] = psv[fr][q];
            }
    }
    __syncthreads();
    if (wn == 1 && lr == 0) {
        #pragma unroll
        for (int fr = 0; fr < 2; fr++)
            #pragma unroll
            for (int q = 0; q < 4; q++) {
                int rl = wm * 32 + fr * 16 + lg * 4 + q;
                int row = bm * 64 + rl;
                si[hd * NN + row] = sred[rl * 2] + pdv[fr][q];
                sj[hd * NN + row] = sred[rl * 2 + 1] + psv[fr][q];
            }
    }
}

// -------- layer-1 attention: 256 thr/node, uint2 (4xbf16) gather ------------
// R1: gather widened 4B->8B per lane (halves load-instr count; two neighbor
// rows in flight: half = tid>>7 handles rows k+half for k += 2), softmax
// normalization deferred to epilogue via invs[head] (kills 3rd LDS pass).
__global__ __launch_bounds__(256) void l1_attn(const int* __restrict__ nbr,
                                               const int* __restrict__ deg,
                                               const unsigned short* __restrict__ hb,
                                               const float* __restrict__ si,
                                               const float* __restrict__ sj,
                                               float* __restrict__ x2) {
    int i = blockIdx.x;
    int tid = threadIdx.x;
    int wave = tid >> 6, lane = tid & 63;
    int d = deg[i];
    __shared__ int js[MAXDEG];
    __shared__ float wls[HH][MAXDEG];
    __shared__ float invs[HH];
    __shared__ __align__(16) float4 red[128];
    for (int k = tid; k < d; k += 256) js[k] = nbr[(size_t)i * MAXDEG + k];
    __syncthreads();

    int hd = wave * 2 + (lane >> 5);
    int l32 = lane & 31;
    float sii = si[hd * NN + i];
    const float* sjh = sj + (size_t)hd * NN;
    float m = -1e30f;
    for (int k = l32; k < d; k += 32) {
        float sc = sii + sjh[js[k]];
        sc = sc > 0.f ? sc : ALPHA * sc;
        wls[hd][k] = sc;
        m = fmaxf(m, sc);
    }
    #pragma unroll
    for (int off = 16; off; off >>= 1) m = fmaxf(m, __shfl_xor(m, off, 64));
    float s = 0.f;
    for (int k = l32; k < d; k += 32) {
        float e = expf(wls[hd][k] - m);
        wls[hd][k] = e;
        s += e;
    }
    #pragma unroll
    for (int off = 16; off; off >>= 1) s += __shfl_xor(s, off, 64);
    if (l32 == 0) invs[hd] = 1.f / fmaxf(s, 1e-30f);
    __syncthreads();

    // gather: thread owns 4 bf16 cols at cq*4 (uint2), rows k+half for k+=2
    const uint2* hu2 = (const uint2*)hb;   // row stride HD/4 = 128
    int half = tid >> 7;
    int cq = tid & 127;
    const float* wl = wls[cq >> 4];
    float a0 = 0.f, a1 = 0.f, a2 = 0.f, a3 = 0.f;
    int kk = half;
    for (; kk + 4 <= d; kk += 4) {
        uint2 v0 = hu2[(size_t)js[kk] * 128 + cq];
        uint2 v1 = hu2[(size_t)js[kk + 2] * 128 + cq];
        float w0 = wl[kk], w1 = wl[kk + 2];
        a0 = fmaf(w0, bf2f((unsigned short)v0.x), a0);
        a1 = fmaf(w0, bf2f((unsigned short)(v0.x >> 16)), a1);
        a2 = fmaf(w0, bf2f((unsigned short)v0.y), a2);
        a3 = fmaf(w0, bf2f((unsigned short)(v0.y >> 16)), a3);
        a0 = fmaf(w1, bf2f((unsigned short)v1.x), a0);
        a1 = fmaf(w1, bf2f((unsigned short)(v1.x >> 16)), a1);
        a2 = fmaf(w1, bf2f((unsigned short)v1.y), a2);
        a3 = fmaf(w1, bf2f((unsigned short)(v1.y >> 16)), a3);
    }
    for (; kk < d; kk += 2) {
        uint2 v = hu2[(size_t)js[kk] * 128 + cq];
        float w = wl[kk];
        a0 = fmaf(w, bf2f((unsigned short)v.x), a0);
        a1 = fmaf(w, bf2f((unsigned short)(v.x >> 16)), a1);
        a2 = fmaf(w, bf2f((unsigned short)v.y), a2);
        a3 = fmaf(w, bf2f((unsigned short)(v.y >> 16)), a3);
    }
    if (half == 1) red[cq] = make_float4(a0, a1, a2, a3);
    __syncthreads();
    if (half == 0) {
        float4 r = red[cq];
        float inv = invs[cq >> 4];
        a0 = (a0 + r.x) * inv;
        a1 = (a1 + r.y) * inv;
        a2 = (a2 + r.z) * inv;
        a3 = (a3 + r.w) * inv;
        float4 o;
        o.x = a0 > 0.f ? a0 : expm1f(a0);  // ELU fused
        o.y = a1 > 0.f ? a1 : expm1f(a1);
        o.z = a2 > 0.f ? a2 : expm1f(a2);
        o.w = a3 > 0.f ? a3 : expm1f(a3);
        *(float4*)(x2 + (size_t)i * HD + cq * 4) = o;
    }
}

// ------ l2 fused: h2 = x2 @ W2p (full-K, BM=16) + d1/d2 reductions ----------
// R1: replaces split-K l2_gemm + l2_post. 256 blocks (1/CU), each owns 16
// complete C-rows -> d1/d2 wave-reduce in-kernel; Cp2 round-trip eliminated.
__global__ __launch_bounds__(256) void l2_fused(const float* __restrict__ x2,
                                                const float* __restrict__ W2p,
                                                const float* __restrict__ a2sf,
                                                const float* __restrict__ a2df,
                                                float* __restrict__ h2,
                                                float* __restrict__ d1,
                                                float* __restrict__ d2) {
    __shared__ __align__(16) float As[L2BK][L2BM + 4];  // [k][r]
    __shared__ float Bs[L2BK][CP + 1];                  // [k][c]
    int tid = threadIdx.x;
    int bm = blockIdx.x;
    int ar = tid >> 4;            // 0..15 A-row
    int ac2 = (tid & 15) * 2;     // A k-pair base
    int br = tid >> 3;            // 0..31 B k-row
    int bc = (tid & 7) * 8;       // B col base
    int c = tid & 63;             // output column
    int r0 = (tid >> 6) * 4;      // wave's 4 output rows

    const float* Arow = x2 + (size_t)(bm * L2BM + ar) * FF;

    float acc0 = 0.f, acc1 = 0.f, acc2 = 0.f, acc3 = 0.f;

    float2 av = *(const float2*)(Arow + ac2);
    float4 bv0 = *(const float4*)(W2p + (size_t)br * CP + bc);
    float4 bv1 = *(const float4*)(W2p + (size_t)br * CP + bc + 4);

    for (int kk = 0; kk < FF; kk += L2BK) {
        __syncthreads();
        As[ac2 + 0][ar] = av.x;
        As[ac2 + 1][ar] = av.y;
        *(float4*)&Bs[br][bc] = bv0;
        *(float4*)&Bs[br][bc + 4] = bv1;
        __syncthreads();
        int kn = (kk + L2BK < FF) ? kk + L2BK : kk;
        av = *(const float2*)(Arow + kn + ac2);
        bv0 = *(const float4*)(W2p + (size_t)(kn + br) * CP + bc);
        bv1 = *(const float4*)(W2p + (size_t)(kn + br) * CP + bc + 4);
        #pragma unroll
        for (int k = 0; k < L2BK; k++) {
            float4 a = *(const float4*)&As[k][r0];
            float b = Bs[k][c];
            acc0 = fmaf(a.x, b, acc0);
            acc1 = fmaf(a.y, b, acc1);
            acc2 = fmaf(a.z, b, acc2);
            acc3 = fmaf(a.w, b, acc3);
        }
    }

    float accs[4] = { acc0, acc1, acc2, acc3 };
    float ad = (c < CC) ? a2df[c] : 0.f;
    float as = (c < CC) ? a2sf[c] : 0.f;
    #pragma unroll
    for (int q = 0; q < 4; q++) {
        int row = bm * L2BM + r0 + q;
        if (c < CC) h2[(size_t)row * CC + c] = accs[q];
        float pd = wave_sum(accs[q] * ad);
        float ps = wave_sum(accs[q] * as);
        if (c == 0) { d1[row] = pd; d2[row] = ps; }
    }
}

// -------- layer-2 attention: 4 nodes per 256-thread block, wave = node ------
__global__ __launch_bounds__(256) void l2_attn(const int* __restrict__ nbr,
                                               const int* __restrict__ deg,
                                               const float* __restrict__ h2,
                                               const float* __restrict__ d1,
                                               const float* __restrict__ d2,
                                               float* __restrict__ out) {
    int w = threadIdx.x >> 6, lane = threadIdx.x & 63;
    int i = blockIdx.x * 4 + w;
    int d = deg[i];
    __shared__ int js[4][MAXDEG];
    __shared__ float wls[4][MAXDEG];
    for (int k = lane; k < d; k += 64) js[w][k] = nbr[(size_t)i * MAXDEG + k];

    float sii = d1[i];
    float m = -1e30f;
    for (int k = lane; k < d; k += 64) {
        float sc = sii + d2[js[w][k]];
        sc = sc > 0.f ? sc : ALPHA * sc;
        wls[w][k] = sc;
        m = fmaxf(m, sc);
    }
    m = wave_max(m);
    float s = 0.f;
    for (int k = lane; k < d; k += 64) {
        float e = expf(wls[w][k] - m);
        wls[w][k] = e;
        s += e;
    }
    s = fmaxf(wave_sum(s), 1e-30f);

    int c = lane;
    if (c < CC) {
        float acc = 0.f;
        int k = 0;
        for (; k + 4 <= d; k += 4) {
            float v0 = h2[(size_t)js[w][k] * CC + c];
            float v1 = h2[(size_t)js[w][k + 1] * CC + c];
            float v2 = h2[(size_t)js[w][k + 2] * CC + c];
            float v3 = h2[(size_t)js[w][k + 3] * CC + c];
            acc = fmaf(wls[w][k], v0, acc);
            acc = fmaf(wls[w][k + 1], v1, acc);
            acc = fmaf(wls[w][k + 2], v2, acc);
            acc = fmaf(wls[w][k + 3], v3, acc);
        }
        for (; k < d; k++)
            acc = fmaf(wls[w][k], h2[(size_t)js[w][k] * CC + c], acc);
        out[(size_t)i * CC + c] = acc / s;
    }
}

extern "C" void kernel_launch(void* const* d_in, const int* in_sizes, int n_in,
                              void* d_out, int out_size, void* d_ws, size_t ws_size,
                              hipStream_t stream) {
    const void* x   = d_in[0];
    const unsigned char* adj = (const unsigned char*)d_in[1];
    const void* W1  = d_in[2];
    const void* a1s = d_in[3];  // a1_src
    const void* a1d = d_in[4];  // a1_dst
    const void* W2  = d_in[5];
    const void* a2s = d_in[6];
    const void* a2d = d_in[7];

    char* ws = (char*)d_ws;
    int*   nbr   = (int*)(ws + 0);                        // 2,097,152
    int*   deg   = (int*)(ws + 2097152);                  // 16,384
    float* si    = (float*)(ws + 2113536);                // 131,072
    float* sj    = (float*)(ws + 2244608);                // 131,072
    unsigned short* W1bth = (unsigned short*)(ws + 2375680);  // 524,288
    unsigned short* W1btl = (unsigned short*)(ws + 2899968);  // 524,288
    float* W2p   = (float*)(ws + 3424256);                // 131,072
    float* a1sf  = (float*)(ws + 3555328);                // 2,048
    float* a1df  = (float*)(ws + 3557376);                // 2,048
    float* a2sf  = (float*)(ws + 3559424);                // 256
    float* a2df  = (float*)(ws + 3559680);                // 256
    unsigned short* hb = (unsigned short*)(ws + 3559936); // 4,194,304 [N][H*D] bf16
    float* x2    = (float*)(ws + 7754240);                // 8,388,608
    float* h2    = (float*)(ws + 16142848);               // 655,360
    float* d1    = (float*)(ws + 16798208);               // 16,384
    float* d2    = (float*)(ws + 16814592);               // 16,384
    // total ~16.8 MB (Cp2 eliminated in R1)

    // prep grid: 4096 nbr rows + 64 W1-transpose blocks + 133 small blocks
    const int nSmall = HD * CP + 2 * HD + 2 * CC;  // 33,872
    const int prepGrid = NN + 64 + (nSmall + 255) / 256;
    hipLaunchKernelGGL(prep, dim3(prepGrid), dim3(256), 0, stream,
                       adj, x, W1, W2, a1s, a1d, a2s, a2d,
                       nbr, deg, W1bth, W1btl, W2p, a1sf, a1df, a2sf, a2df);

    hipLaunchKernelGGL(l1_gemm, dim3(NN / 64, HH), dim3(256), 0, stream,
                       x, W1bth, W1btl, a1sf, a1df, hb, si, sj);
    hipLaunchKernelGGL(l1_attn, dim3(NN), dim3(256), 0, stream,
                       nbr, deg, hb, si, sj, x2);
    hipLaunchKernelGGL(l2_fused, dim3(NN / L2BM), dim3(256), 0, stream,
                       x2, W2p, a2sf, a2df, h2, d1, d2);
    hipLaunchKernelGGL(l2_attn, dim3(NN / 4), dim3(256), 0, stream,
                       nbr, deg, h2, d1, d2, (float*)d_out);
}